// Round 10
// baseline (29509.811 us; speedup 1.0000x reference)
//
#include <hip/hip_runtime.h>
#include <stdint.h>

// ============================================================
// AdaptiveLNN on MI355X, round 9: cut LDS activation-broadcast traffic.
// Scan matvec = 2 outputs/thread (p, p+256) x 4-way k-split; activation
// k-dim re-paired as slot s=(h[s],h[s+256]) at weight-pack time so each
// thread writes its own slot. Pipeline/ring/Wrec-LDS cache from r9.
// ============================================================

__device__ __forceinline__ float b2f(unsigned short s){
  union { unsigned i; float f; } c; c.i = ((unsigned)s) << 16; return c.f;
}
__device__ __forceinline__ unsigned short f2b(float f){
  union { unsigned i; float f; } c; c.f = f;
  unsigned r = c.i + 0x7fffu + ((c.i >> 16) & 1u);
  return (unsigned short)(r >> 16);
}
__device__ __forceinline__ unsigned pack2(float a, float b){
  return (unsigned)f2b(a) | ((unsigned)f2b(b) << 16);
}
__device__ __forceinline__ float fsig(float x){ return 1.f/(1.f+__expf(-x)); }
__device__ __forceinline__ float ftanh(float x){ return 1.f - 2.f/(__expf(2.f*x)+1.f); }

#if __has_builtin(__builtin_amdgcn_fdot2_f32_bf16)
typedef __bf16 bf16x2_t __attribute__((ext_vector_type(2)));
__device__ __forceinline__ float dot2(unsigned w, unsigned a, float acc){
  union U { unsigned u; bf16x2_t v; };
  U cw; cw.u = w; U ca; ca.u = a;
  return __builtin_amdgcn_fdot2_f32_bf16(cw.v, ca.v, acc, false);
}
#else
__device__ __forceinline__ float dot2(unsigned w, unsigned a, float acc){
  asm("v_dot2_f32_bf16 %0, %1, %2, %0" : "+v"(acc) : "v"(w), "v"(a));
  return acc;
}
#endif

// ---------- scan matvec: 1024 thr, p=tid>>2 owns {p, 256+p}, c=tid&3 ----------
template<int K>
__device__ __forceinline__ void matvecS(const uint4* __restrict__ w,
                                        const unsigned* __restrict__ act2,
                                        int tid, float* out){
  constexpr int NI = K / 32;
  const uint4* a4 = (const uint4*)act2;
  const int c = tid & 3;
  float acc0 = 0.f, acc1 = 0.f;
  #pragma unroll 4
  for (int i = 0; i < NI; ++i){
    const uint4 a  = a4[i*4 + c];
    const uint4 w0 = w[(size_t)(i*2+0)*1024 + tid];
    const uint4 w1 = w[(size_t)(i*2+1)*1024 + tid];
    acc0 = dot2(w0.x, a.x, acc0); acc0 = dot2(w0.y, a.y, acc0);
    acc0 = dot2(w0.z, a.z, acc0); acc0 = dot2(w0.w, a.w, acc0);
    acc1 = dot2(w1.x, a.x, acc1); acc1 = dot2(w1.y, a.y, acc1);
    acc1 = dot2(w1.z, a.z, acc1); acc1 = dot2(w1.w, a.w, acc1);
  }
  acc0 += __shfl_xor(acc0, 1); acc0 += __shfl_xor(acc0, 2);
  acc1 += __shfl_xor(acc1, 1); acc1 += __shfl_xor(acc1, 2);
  out[0] = acc0; out[1] = acc1;
}

// ---------- Wrec matvec, slots idx=i*2+j, idx<9 LDS-cached ----------
template<bool FILL>
__device__ __forceinline__ void wrecS(const uint4* __restrict__ w,
                                      const unsigned* __restrict__ act2,
                                      uint4* __restrict__ wlds,
                                      int tid, float* out){
  const uint4* a4 = (const uint4*)act2;
  const int c = tid & 3;
  float acc0 = 0.f, acc1 = 0.f;
  #pragma unroll
  for (int i = 0; i < 4; ++i){
    const uint4 a = a4[i*4 + c];
    uint4 w0, w1;
    if (FILL){
      w0 = w[(size_t)(i*2+0)*1024 + tid]; wlds[(i*2+0)*1024 + tid] = w0;
      w1 = w[(size_t)(i*2+1)*1024 + tid]; wlds[(i*2+1)*1024 + tid] = w1;
    } else {
      w0 = wlds[(i*2+0)*1024 + tid];
      w1 = wlds[(i*2+1)*1024 + tid];
    }
    acc0 = dot2(w0.x, a.x, acc0); acc0 = dot2(w0.y, a.y, acc0);
    acc0 = dot2(w0.z, a.z, acc0); acc0 = dot2(w0.w, a.w, acc0);
    acc1 = dot2(w1.x, a.x, acc1); acc1 = dot2(w1.y, a.y, acc1);
    acc1 = dot2(w1.z, a.z, acc1); acc1 = dot2(w1.w, a.w, acc1);
  }
  {
    const uint4 a = a4[16 + c];
    uint4 w0;
    if (FILL){ w0 = w[(size_t)8*1024 + tid]; wlds[8*1024 + tid] = w0; }
    else     { w0 = wlds[8*1024 + tid]; }
    const uint4 w1 = w[(size_t)9*1024 + tid];
    acc0 = dot2(w0.x, a.x, acc0); acc0 = dot2(w0.y, a.y, acc0);
    acc0 = dot2(w0.z, a.z, acc0); acc0 = dot2(w0.w, a.w, acc0);
    acc1 = dot2(w1.x, a.x, acc1); acc1 = dot2(w1.y, a.y, acc1);
    acc1 = dot2(w1.z, a.z, acc1); acc1 = dot2(w1.w, a.w, acc1);
  }
  #pragma unroll 2
  for (int i = 5; i < 16; ++i){
    const uint4 a  = a4[i*4 + c];
    const uint4 w0 = w[(size_t)(i*2+0)*1024 + tid];
    const uint4 w1 = w[(size_t)(i*2+1)*1024 + tid];
    acc0 = dot2(w0.x, a.x, acc0); acc0 = dot2(w0.y, a.y, acc0);
    acc0 = dot2(w0.z, a.z, acc0); acc0 = dot2(w0.w, a.w, acc0);
    acc1 = dot2(w1.x, a.x, acc1); acc1 = dot2(w1.y, a.y, acc1);
    acc1 = dot2(w1.z, a.z, acc1); acc1 = dot2(w1.w, a.w, acc1);
  }
  acc0 += __shfl_xor(acc0, 1); acc0 += __shfl_xor(acc0, 2);
  acc1 += __shfl_xor(acc1, 1); acc1 += __shfl_xor(acc1, 2);
  out[0] = acc0; out[1] = acc1;
}

// ---------- one LTC layer, one timestep (2 outputs/thread) ----------
template<int KC, int KI>
__device__ __forceinline__ void layer_stepQ(
    float& v0, float& g0, float& v1, float& g1,
    const uint4* Wi, const uint4* Wr, const uint4* Ta, const uint4* Tb,
    const float* pvec, int cb,
    unsigned* comb2, unsigned* thA, unsigned* thB, float* sred,
    uint4* wlds, int tid, bool fill, float& y0, float& y1)
{
  const int p = tid >> 2;
  float th2[2]; matvecS<KC>(Ta, comb2, tid, th2);
  float ii[2];  matvecS<KI>(Wi, comb2, tid, ii);
  const float tauh0 = ftanh(th2[0] + pvec[cb+512+p]);
  const float tauh1 = ftanh(th2[1] + pvec[cb+768+p]);
  const float iin0  = ii[0] + pvec[cb+p];
  const float iin1  = ii[1] + pvec[cb+256+p];
  float h0 = ftanh(v0), h1 = ftanh(v1);
  if (!(tid & 3)){ thA[p] = pack2(tauh0, tauh1); thB[p] = pack2(h0, h1); }
  __syncthreads();
  float tt[2]; matvecS<512>(Tb, thA, tid, tt);
  const float tau0 = 0.1f + 9.9f * fsig(tt[0] + pvec[cb+1024+p]);
  const float tau1 = 0.1f + 9.9f * fsig(tt[1] + pvec[cb+1280+p]);
  const float ga0 = 0.2f/tau0, va0 = 0.1f/tau0;
  const float ga1 = 0.2f/tau1, va1 = 0.1f/tau1;
  const float gl0 = pvec[cb+1536+p], gl1 = pvec[cb+1792+p];
  const float gs0 = pvec[cb+2048+p], gs1 = pvec[cb+2304+p];
  __syncthreads();
  #pragma unroll 1
  for (int u = 0; u < 6; ++u){
    unsigned* cur = (u & 1) ? thA : thB;
    unsigned* nxt = (u & 1) ? thB : thA;
    float ir[2];
    if (fill && u == 0) wrecS<true >(Wr, cur, wlds, tid, ir);
    else                wrecS<false>(Wr, cur, wlds, tid, ir);
    g0 += (fsig(iin0 + ir[0]) - g0) * ga0;
    v0 += (gs0*g0*(1.f - v0) - gl0*v0) * va0;
    v0 = fminf(5.f, fmaxf(-5.f, v0)); h0 = ftanh(v0);
    g1 += (fsig(iin1 + ir[1]) - g1) * ga1;
    v1 += (gs1*g1*(1.f - v1) - gl1*v1) * va1;
    v1 = fminf(5.f, fmaxf(-5.f, v1)); h1 = ftanh(v1);
    if (!(tid & 3)) nxt[p] = pack2(h0, h1);
    __syncthreads();
  }
  float s1 = (tid & 3) ? 0.f : (h0 + h1);
  float s2 = (tid & 3) ? 0.f : (h0*h0 + h1*h1);
  #pragma unroll
  for (int off = 32; off >= 1; off >>= 1){
    s1 += __shfl_down(s1, off);
    s2 += __shfl_down(s2, off);
  }
  const int lane = tid & 63, wid = tid >> 6;
  if (lane == 0){ sred[wid] = s1; sred[16 + wid] = s2; }
  __syncthreads();
  float S1 = 0.f, S2 = 0.f;
  #pragma unroll
  for (int w2 = 0; w2 < 16; ++w2){ S1 += sred[w2]; S2 += sred[16 + w2]; }
  const float m    = S1 * (1.f/512.f);
  const float varr = S2 * (1.f/512.f) - m * m;
  const float rs   = rsqrtf(varr + 1e-5f);
  y0 = (h0 - m)*rs*pvec[cb+2560+p] + pvec[cb+3072+p];
  y1 = (h1 - m)*rs*pvec[cb+2816+p] + pvec[cb+3328+p];
  __syncthreads();
}

// ---------- 512-thread matvec (tail), r8 layout ----------
template<int K, int NOUT>
__device__ __forceinline__ void matvec2(const uint4* __restrict__ w,
                                        const unsigned* __restrict__ act2,
                                        int tid, float* out){
  constexpr int NJ = NOUT/256, NIB = K/16;
  const uint4* a4 = (const uint4*)act2;
  const int kh = tid & 1;
  float acc[NJ];
  #pragma unroll
  for (int j = 0; j < NJ; ++j) acc[j] = 0.f;
  #pragma unroll 2
  for (int ib = 0; ib < NIB; ++ib){
    const uint4 a = a4[2*ib + kh];
    #pragma unroll
    for (int j = 0; j < NJ; ++j){
      const uint4 wv = w[(size_t)(ib*NJ + j)*512 + tid];
      acc[j] = dot2(wv.x, a.x, acc[j]);
      acc[j] = dot2(wv.y, a.y, acc[j]);
      acc[j] = dot2(wv.z, a.z, acc[j]);
      acc[j] = dot2(wv.w, a.w, acc[j]);
    }
  }
  #pragma unroll
  for (int j = 0; j < NJ; ++j){
    float s = acc[j];
    s += __shfl_xor(s, 1);
    out[j] = s;
  }
}

// ---------- packed-weight offsets (uint4 units) ----------
#define PK_WIN0   0
#define PK_WREC0  16384
#define PK_TA0    49152
#define PK_TB0    98304
#define PK_WIN1   131072
#define PK_WREC1  163840
#define PK_TA1    196608
#define PK_TB1    262144
#define PK_WQ     294912
#define PK_WK     327680
#define PK_WV     360448
#define PK_AO     393216
#define PK_P1     425984
#define PK_P2     442368
#define PK_TOTAL  450560

__global__ void detect_kernel(const unsigned* __restrict__ x, int* __restrict__ flag){
  int cnt = 0;
  for (int i = threadIdx.x; i < 4096; i += 256){
    const unsigned e = (x[i] >> 7) & 0xFFu;
    cnt += (e == 0u || e == 0xFFu) ? 1 : 0;
  }
  __shared__ int sh[4];
  #pragma unroll
  for (int off = 32; off >= 1; off >>= 1) cnt += __shfl_down(cnt, off);
  if ((threadIdx.x & 63) == 0) sh[threadIdx.x >> 6] = cnt;
  __syncthreads();
  if (threadIdx.x == 0) *flag = (sh[0]+sh[1]+sh[2]+sh[3] > 4) ? 1 : 0;
}

// slot map: s < xs -> (2s, 2s+1); else sv=s-xs -> lo=2*xs+(sv>>8)*512+(sv&255), hi=lo+256
struct PackDesc {
  const void* src[14];
  long eoff[14];
  int kdim[14];
  int lg2n[14];
  int mode[14];
  int xs[14];
  int cum[15];
};
__global__ void pack_kernel(PackDesc d, const int* __restrict__ flag,
                            uint4* __restrict__ out){
  const int u = blockIdx.x * 256 + threadIdx.x;
  if (u >= d.cum[14]) return;
  int s = 0;
  #pragma unroll
  for (int i = 1; i < 14; ++i) if (u >= d.cum[i]) s = i;
  const int local = u - d.cum[s];
  const int K = d.kdim[s];
  int o, m;
  if (d.mode[s] == 0){
    const int tid = local & 1023;
    const int r   = local >> 10;
    o = (r & 1)*256 + (tid >> 2);
    m = (r >> 1)*4 + (tid & 3);
  } else {
    const int tid  = local & 511;
    const int r    = local >> 9;
    const int lgnj = d.lg2n[s] - 8;
    const int j    = r & ((1 << lgnj) - 1);
    const int ib   = r >> lgnj;
    o = (j << 8) + (tid >> 1);
    m = 2*ib + (tid & 1);
  }
  const int xs = d.xs[s];
  const int isf = *flag;
  unsigned res[4];
  #pragma unroll
  for (int c2 = 0; c2 < 4; ++c2){
    const int sl = 4*m + c2;
    int lo, hi;
    if (sl < xs){ lo = 2*sl; hi = lo + 1; }
    else {
      const int sv = sl - xs;
      lo = 2*xs + ((sv >> 8) << 9) + (sv & 255);
      hi = lo + 256;
    }
    unsigned short a, b;
    if (isf){
      const float* sp = (const float*)d.src[s] + d.eoff[s] + (long)o*K;
      a = f2b(sp[lo]); b = f2b(sp[hi]);
    } else {
      const unsigned short* sp = (const unsigned short*)d.src[s] + d.eoff[s] + (long)o*K;
      a = sp[lo]; b = sp[hi];
    }
    res[c2] = (unsigned)a | ((unsigned)b << 16);
  }
  uint4 o4; o4.x = res[0]; o4.y = res[1]; o4.z = res[2]; o4.w = res[3];
  out[u] = o4;
}

struct VecDesc {
  const void* src[18];
  int n[18];
  int dst[18];
};
__global__ void vec_kernel(VecDesc d, const int* __restrict__ flag,
                           float* __restrict__ pvec){
  const int s = blockIdx.x;
  const int f = *flag;
  for (int i = threadIdx.x; i < d.n[s]; i += blockDim.x)
    pvec[d.dst[s] + i] = f ? ((const float*)d.src[s])[i]
                           : b2f(((const unsigned short*)d.src[s])[i]);
}

__global__ void zflags_kernel(int* __restrict__ aflag, int* __restrict__ cflag){
  const int i = threadIdx.x;
  if (i < 64) aflag[i] = 0; else cflag[i - 64] = 0;
}

// ---------- layer-pipelined scan: 128 blocks x 1024 threads ----------
#define SCAN_SMEM 151680
__global__ __launch_bounds__(1024) void scan_kernel(
    const void* __restrict__ xin,
    const uint4* __restrict__ wp,
    const float* __restrict__ pvec,
    const int* __restrict__ flagp,
    unsigned* __restrict__ seqw,
    unsigned* __restrict__ ring,
    int* __restrict__ aflag,
    int* __restrict__ cflag)
{
  extern __shared__ __align__(16) char smem[];
  unsigned* comb2 = (unsigned*)smem;
  unsigned* thA   = comb2 + 512;
  unsigned* thB   = thA + 256;
  float*    sred  = (float*)(thB + 256);
  uint4*    wlds  = (uint4*)(smem + 4224);

  const int tid = threadIdx.x;
  const int p   = tid >> 2;
  const int blk = blockIdx.x;
  const int b   = blk & 63;
  const bool isB = blk >= 64;
  const int isf32 = *flagp;
  const int cb  = isB ? 3584 : 0;

  const uint4* Ta = wp + (isB ? PK_TA1  : PK_TA0);
  const uint4* Tb = wp + (isB ? PK_TB1  : PK_TB0);
  const uint4* Wi = wp + (isB ? PK_WIN1 : PK_WIN0);
  const uint4* Wr = wp + (isB ? PK_WREC1: PK_WREC0);

  float v0 = 0.f, g0 = 0.f, v1 = 0.f, g1 = 0.f;

  #pragma unroll 1
  for (int t = 0; t < 512; ++t){
    if (!isB){
      if (tid < 128){
        const size_t idx = ((size_t)b*512 + t)*128 + tid;
        if (isf32){
          const float2 xv = ((const float2*)xin)[idx];
          comb2[tid] = pack2(xv.x, xv.y);
        } else {
          comb2[tid] = ((const unsigned*)xin)[idx];
        }
      }
      if (!(tid & 3)) comb2[128 + p] = pack2(v0, v1);
      __syncthreads();
      float y0, y1;
      layer_stepQ<768, 256>(v0, g0, v1, g1, Wi, Wr, Ta, Tb, pvec, cb,
                            comb2, thA, thB, sred, wlds, tid, t == 0, y0, y1);
      if (tid == 0 && t >= 8){
        while (__hip_atomic_load(&cflag[b], __ATOMIC_ACQUIRE,
                                 __HIP_MEMORY_SCOPE_AGENT) < t - 7)
          __builtin_amdgcn_s_sleep(1);
      }
      __syncthreads();
      if (!(tid & 3)){
        unsigned* dst = ring + ((size_t)b*8 + (t & 7))*256;
        __hip_atomic_store(dst + p, pack2(y0, y1),
                           __ATOMIC_RELAXED, __HIP_MEMORY_SCOPE_AGENT);
      }
      __syncthreads();
      if (tid == 0)
        __hip_atomic_store(&aflag[b], t + 1, __ATOMIC_RELEASE,
                           __HIP_MEMORY_SCOPE_AGENT);
    } else {
      if (tid == 0){
        while (__hip_atomic_load(&aflag[b], __ATOMIC_ACQUIRE,
                                 __HIP_MEMORY_SCOPE_AGENT) < t + 1)
          __builtin_amdgcn_s_sleep(1);
      }
      __syncthreads();
      if (tid < 256){
        const unsigned* src = ring + ((size_t)b*8 + (t & 7))*256;
        comb2[tid] = __hip_atomic_load(src + tid, __ATOMIC_RELAXED,
                                       __HIP_MEMORY_SCOPE_AGENT);
      }
      if (!(tid & 3)) comb2[256 + p] = pack2(v0, v1);
      __syncthreads();
      if (tid == 0)
        __hip_atomic_store(&cflag[b], t + 1, __ATOMIC_RELEASE,
                           __HIP_MEMORY_SCOPE_AGENT);
      float y0, y1;
      layer_stepQ<1024, 512>(v0, g0, v1, g1, Wi, Wr, Ta, Tb, pvec, cb,
                             comb2, thA, thB, sred, wlds, tid, t == 0, y0, y1);
      if (!(tid & 3))
        seqw[((size_t)b*512 + t)*256 + p] = pack2(y0, y1);
    }
  }
}

__global__ __launch_bounds__(512) void q_kernel(
    const unsigned* __restrict__ seqw, const uint4* __restrict__ wp,
    const float* __restrict__ pvec, float* __restrict__ qws)
{
  __shared__ __align__(16) unsigned act2[256];
  const int tid = threadIdx.x, b = blockIdx.x, p = tid >> 1;
  if (tid < 256) act2[tid] = seqw[((size_t)(b*512 + 511))*256 + tid];
  __syncthreads();
  float q[2]; matvec2<512, 512>(wp + PK_WQ, act2, tid, q);
  if (!(tid & 1)){
    qws[b*512 + p]       = q[0] + pvec[7168 + p];
    qws[b*512 + 256 + p] = q[1] + pvec[7168 + 256 + p];
  }
}

__global__ __launch_bounds__(512) void score_kernel(
    const unsigned* __restrict__ seqw, const uint4* __restrict__ wp,
    const float* __restrict__ pvec, const float* __restrict__ qws,
    float* __restrict__ sws)
{
  __shared__ __align__(16) unsigned act2[256];
  __shared__ float hrA[8], hrB[8];
  const int tid = threadIdx.x, p = tid >> 1;
  const int r = blockIdx.x, b = r >> 9, t = r & 511;
  if (tid < 256) act2[tid] = seqw[(size_t)r*256 + tid];
  __syncthreads();
  float kk[2]; matvec2<512, 512>(wp + PK_WK, act2, tid, kk);
  float pa = (tid & 1) ? 0.f : (kk[0] + pvec[7680 + p])       * qws[b*512 + p];
  float pb = (tid & 1) ? 0.f : (kk[1] + pvec[7680 + 256 + p]) * qws[b*512 + 256 + p];
  #pragma unroll
  for (int off = 32; off >= 1; off >>= 1){
    pa += __shfl_down(pa, off); pb += __shfl_down(pb, off);
  }
  const int lane = tid & 63, wid = tid >> 6;
  if (lane == 0){ hrA[wid] = pa; hrB[wid] = pb; }
  __syncthreads();
  if (tid < 4){
    float s;
    if      (tid == 0) s = hrA[0]+hrA[1]+hrA[2]+hrA[3];
    else if (tid == 1) s = hrA[4]+hrA[5]+hrA[6]+hrA[7];
    else if (tid == 2) s = hrB[0]+hrB[1]+hrB[2]+hrB[3];
    else               s = hrB[4]+hrB[5]+hrB[6]+hrB[7];
    sws[((size_t)(b*4 + tid))*512 + t] = s * 0.08838834764831845f;
  }
}

__global__ __launch_bounds__(512) void softmax_kernel(
    const float* __restrict__ sws, float* __restrict__ pws,
    float* __restrict__ oacc)
{
  __shared__ float rw[16];
  const int tid = threadIdx.x, bh = blockIdx.x;
  const float s = sws[(size_t)bh*512 + tid];
  float mx = s;
  #pragma unroll
  for (int off = 32; off >= 1; off >>= 1) mx = fmaxf(mx, __shfl_down(mx, off));
  const int lane = tid & 63, wid = tid >> 6;
  if (lane == 0) rw[wid] = mx;
  __syncthreads();
  mx = rw[0];
  #pragma unroll
  for (int w2 = 1; w2 < 8; ++w2) mx = fmaxf(mx, rw[w2]);
  const float e = __expf(s - mx);
  float sm = e;
  #pragma unroll
  for (int off = 32; off >= 1; off >>= 1) sm += __shfl_down(sm, off);
  if (lane == 0) rw[8 + wid] = sm;
  __syncthreads();
  sm = 0.f;
  #pragma unroll
  for (int w2 = 0; w2 < 8; ++w2) sm += rw[8 + w2];
  pws[(size_t)bh*512 + tid] = e / sm;
  if (tid < 128) oacc[(bh >> 2)*512 + (bh & 3)*128 + tid] = 0.f;
}

__global__ __launch_bounds__(512) void vacc_kernel(
    const unsigned* __restrict__ seqw, const uint4* __restrict__ wp,
    const float* __restrict__ pvec, const float* __restrict__ pws,
    float* __restrict__ oacc)
{
  __shared__ __align__(16) unsigned act2[256];
  const int tid = threadIdx.x, p = tid >> 1;
  const int blk = blockIdx.x, b = blk >> 3, ch = blk & 7;
  float a0 = 0.f, a1 = 0.f;
  #pragma unroll 1
  for (int t = ch*64; t < ch*64 + 64; ++t){
    if (tid < 256) act2[tid] = seqw[((size_t)b*512 + t)*256 + tid];
    __syncthreads();
    float vv[2]; matvec2<512, 512>(wp + PK_WV, act2, tid, vv);
    if (!(tid & 1)){
      a0 += (vv[0] + pvec[8192 + p])       * pws[(size_t)(b*4 + (p>>7))*512 + t];
      a1 += (vv[1] + pvec[8192 + 256 + p]) * pws[(size_t)(b*4 + 2 + (p>>7))*512 + t];
    }
    __syncthreads();
  }
  if (!(tid & 1)){
    atomicAdd(&oacc[b*512 + p], a0);
    atomicAdd(&oacc[b*512 + 256 + p], a1);
  }
}

__global__ __launch_bounds__(512) void final_kernel(
    const float* __restrict__ oacc, const uint4* __restrict__ wp,
    const float* __restrict__ pvec, const int* __restrict__ flagp,
    void* __restrict__ out)
{
  __shared__ __align__(16) unsigned a2[256];
  const int tid = threadIdx.x, b = blockIdx.x, p = tid >> 1;
  const int isf32 = *flagp;
  {
    const float x0 = oacc[b*512 + p], x1 = oacc[b*512 + 256 + p];
    const float xa = __shfl_down(x0, 2), xb = __shfl_down(x1, 2);
    if (!(tid & 3)){ a2[tid>>2] = pack2(x0, xa); a2[128+(tid>>2)] = pack2(x1, xb); }
  }
  __syncthreads();
  float t1[2]; matvec2<512, 512>(wp + PK_AO, a2, tid, t1);
  t1[0] += pvec[8704 + p]; t1[1] += pvec[8704 + 256 + p];
  __syncthreads();
  {
    const float ta = __shfl_down(t1[0], 2), tb = __shfl_down(t1[1], 2);
    if (!(tid & 3)){ a2[tid>>2] = pack2(t1[0], ta); a2[128+(tid>>2)] = pack2(t1[1], tb); }
  }
  __syncthreads();
  float t2[1]; matvec2<512, 256>(wp + PK_P1, a2, tid, t2);
  t2[0] = fmaxf(0.f, t2[0] + pvec[9216 + p]);
  __syncthreads();
  {
    const float ta = __shfl_down(t2[0], 2);
    if (!(tid & 3)) a2[tid>>2] = pack2(t2[0], ta);
  }
  __syncthreads();
  float r[1]; matvec2<256, 256>(wp + PK_P2, a2, tid, r);
  if (!(tid & 1)){
    const float rr = r[0] + pvec[9472 + p];
    if (isf32) ((float*)out)[b*256 + p] = rr;
    else       ((unsigned short*)out)[b*256 + p] = f2b(rr);
  }
}

__global__ void zero_kernel(unsigned* __restrict__ p, int n){
  const int i = blockIdx.x * 1024 + threadIdx.x;
  if (i < n) p[i] = 0;
}

// ============================================================
extern "C" void kernel_launch(void* const* d_in, const int* in_sizes, int n_in,
                              void* d_out, int out_size, void* d_ws, size_t ws_size,
                              hipStream_t stream)
{
  (void)in_sizes; (void)n_in; (void)out_size;

  if (ws_size < ((size_t)44 << 20)){
    zero_kernel<<<8, 1024, 0, stream>>>((unsigned*)d_out, 8192);
    return;
  }

  hipFuncSetAttribute((const void*)scan_kernel,
                      hipFuncAttributeMaxDynamicSharedMemorySize, SCAN_SMEM);

  char* ws = (char*)d_ws;
  int*      flag   = (int*)ws;
  int*      aflag  = (int*)(ws + 256);
  int*      cflag  = (int*)(ws + 512);
  float*    pvec   = (float*)(ws + 4096);
  uint4*    packed = (uint4*)(ws + 65536);
  unsigned* seq    = (unsigned*)(ws + ((size_t)8 << 20));
  unsigned* ring   = (unsigned*)(ws + ((size_t)40 << 20));
  float*    sws    = (float*)(ws + ((size_t)41 << 20));
  float*    pws    = (float*)(ws + ((size_t)41 << 20) + 524288);
  float*    qws    = (float*)(ws + ((size_t)42 << 20));
  float*    oacc   = (float*)(ws + ((size_t)42 << 20) + 262144);

  detect_kernel<<<1, 256, 0, stream>>>((const unsigned*)d_in[0], flag);
  zflags_kernel<<<1, 128, 0, stream>>>(aflag, cflag);

  PackDesc pd;
  const void* msrc[14] = {
    d_in[1], d_in[3], d_in[4], d_in[6],
    d_in[12], d_in[14], d_in[15], d_in[17],
    d_in[23], d_in[23], d_in[23],
    d_in[25], d_in[27], d_in[29]
  };
  const long eoff[14] = {0,0,0,0, 0,0,0,0, 0, 262144, 524288, 0, 0, 0};
  const int kd[14]   = {256,512,768,512, 512,512,1024,512, 512,512,512, 512, 512, 256};
  const int ln2[14]  = {9,9,9,9, 9,9,9,9, 9,9,9, 9, 8, 8};
  const int mode[14] = {0,0,0,0, 0,0,0,0, 1,1,1, 1, 1, 1};
  const int xsv[14]  = {128,0,128,0, 0,0,0,0, 0,0,0, 256, 256, 128};
  const int cum[15]  = {0,16384,49152,98304,131072,163840,196608,262144,
                        294912,327680,360448,393216,425984,442368,450560};
  for (int i = 0; i < 14; ++i){
    pd.src[i]=msrc[i]; pd.eoff[i]=eoff[i]; pd.kdim[i]=kd[i];
    pd.lg2n[i]=ln2[i]; pd.mode[i]=mode[i]; pd.xs[i]=xsv[i];
  }
  for (int i = 0; i < 15; ++i) pd.cum[i] = cum[i];
  pack_kernel<<<(PK_TOTAL + 255)/256, 256, 0, stream>>>(pd, flag, packed);

  VecDesc vd;
  const void* vsrc[18] = {
    d_in[2], d_in[5], d_in[7], d_in[8], d_in[9], d_in[10], d_in[11],
    d_in[13], d_in[16], d_in[18], d_in[19], d_in[20], d_in[21], d_in[22],
    d_in[24], d_in[26], d_in[28], d_in[30]
  };
  const int vn[18]  = {512,512,512,512,512,512,512, 512,512,512,512,512,512,512,
                       1536,512,256,256};
  const int vds[18] = {0,512,1024,1536,2048,2560,3072,
                       3584,4096,4608,5120,5632,6144,6656,
                       7168,8704,9216,9472};
  for (int i = 0; i < 18; ++i){ vd.src[i]=vsrc[i]; vd.n[i]=vn[i]; vd.dst[i]=vds[i]; }
  vec_kernel<<<18, 512, 0, stream>>>(vd, flag, pvec);

  scan_kernel<<<128, 1024, SCAN_SMEM, stream>>>(d_in[0], packed, pvec, flag,
                                                seq, ring, aflag, cflag);
  q_kernel<<<64, 512, 0, stream>>>(seq, packed, pvec, qws);
  score_kernel<<<64*512, 512, 0, stream>>>(seq, packed, pvec, qws, sws);
  softmax_kernel<<<256, 512, 0, stream>>>(sws, pws, oacc);
  vacc_kernel<<<512, 512, 0, stream>>>(seq, packed, pvec, pws, oacc);
  final_kernel<<<64, 512, 0, stream>>>(oacc, packed, pvec, flag, d_out);
}